// Round 16
// baseline (312.918 us; speedup 1.0000x reference)
//
#include <hip/hip_runtime.h>
#include <hip/hip_bf16.h>

#define N_NODES 100000
#define N_EDGES 1600000
#define IN_DIM 128
#define HID 64
#define NB ((N_NODES + 255) / 256)          // 391 buckets of 256 dst nodes
#define EPB 2048                            // edges per k_bucket block
#define BUCKET_BLOCKS ((N_EDGES + EPB - 1) / EPB)  // 782

// ---------------- threefry2x32, key = (0, 42) ----------------
__device__ __forceinline__ unsigned rotl32(unsigned x, unsigned r) {
    return (x << r) | (x >> (32u - r));
}

__device__ __forceinline__ void threefry2x32_k42(unsigned x0, unsigned x1,
                                                 unsigned& o0, unsigned& o1) {
    const unsigned ks0 = 0u;
    const unsigned ks1 = 42u;
    const unsigned ks2 = 0u ^ 42u ^ 0x1BD11BDAu;
    x0 += ks0; x1 += ks1;
    x0 += x1; x1 = rotl32(x1, 13); x1 ^= x0;
    x0 += x1; x1 = rotl32(x1, 15); x1 ^= x0;
    x0 += x1; x1 = rotl32(x1, 26); x1 ^= x0;
    x0 += x1; x1 = rotl32(x1, 6);  x1 ^= x0;
    x0 += ks1; x1 += ks2 + 1u;
    x0 += x1; x1 = rotl32(x1, 17); x1 ^= x0;
    x0 += x1; x1 = rotl32(x1, 29); x1 ^= x0;
    x0 += x1; x1 = rotl32(x1, 16); x1 ^= x0;
    x0 += x1; x1 = rotl32(x1, 24); x1 ^= x0;
    x0 += ks2; x1 += ks0 + 2u;
    x0 += x1; x1 = rotl32(x1, 13); x1 ^= x0;
    x0 += x1; x1 = rotl32(x1, 15); x1 ^= x0;
    x0 += x1; x1 = rotl32(x1, 26); x1 ^= x0;
    x0 += x1; x1 = rotl32(x1, 6);  x1 ^= x0;
    x0 += ks0; x1 += ks1 + 3u;
    x0 += x1; x1 = rotl32(x1, 17); x1 ^= x0;
    x0 += x1; x1 = rotl32(x1, 29); x1 ^= x0;
    x0 += x1; x1 = rotl32(x1, 16); x1 ^= x0;
    x0 += x1; x1 = rotl32(x1, 24); x1 ^= x0;
    x0 += ks1; x1 += ks2 + 4u;
    x0 += x1; x1 = rotl32(x1, 13); x1 ^= x0;
    x0 += x1; x1 = rotl32(x1, 15); x1 ^= x0;
    x0 += x1; x1 = rotl32(x1, 26); x1 ^= x0;
    x0 += x1; x1 = rotl32(x1, 6);  x1 ^= x0;
    x0 += ks2; x1 += ks0 + 5u;
    o0 = x0; o1 = x1;
}

__device__ __forceinline__ float bf2f(unsigned short u) {
    return __uint_as_float((unsigned)u << 16);
}

// ---------------- per-node degree (edge_index is int32 — proven round 2≡3) ----
__global__ void k_hist(const int* __restrict__ dst, int* __restrict__ cnt) {
    int e = blockIdx.x * 256 + threadIdx.x;
    if (e < N_EDGES) atomicAdd(&cnt[dst[e]], 1);
}

// per-bucket edge totals + dinv
__global__ __launch_bounds__(256) void k_scanA(const int* __restrict__ cnt,
                                               int* __restrict__ bucketsum,
                                               float* __restrict__ dinv) {
    __shared__ int s[256];
    int t = threadIdx.x, i = blockIdx.x * 256 + t;
    int v = (i < N_NODES) ? cnt[i] : 0;
    if (i < N_NODES) dinv[i] = rsqrtf((float)(v + 1));
    s[t] = v;
    __syncthreads();
    for (int st = 128; st; st >>= 1) {
        if (t < st) s[t] += s[t + st];
        __syncthreads();
    }
    if (t == 0) bucketsum[blockIdx.x] = s[0];
}

// exclusive scan over NB bucket sums -> bucket_base, gcur
__global__ __launch_bounds__(512) void k_scanB(const int* __restrict__ bucketsum,
                                               int* __restrict__ bucket_base,
                                               int* __restrict__ gcur) {
    __shared__ int s[512];
    int t = threadIdx.x;
    int own = (t < NB) ? bucketsum[t] : 0;
    s[t] = own;
    __syncthreads();
    for (int o = 1; o < 512; o <<= 1) {
        int v = (t >= o) ? s[t - o] : 0;
        __syncthreads();
        s[t] += v;
        __syncthreads();
    }
    if (t < NB) {
        int ex = s[t] - own;
        bucket_base[t] = ex;
        gcur[t] = ex;
    }
    if (t == 511) bucket_base[NB] = s[511];  // = N_EDGES
}

// ------ g = (x @ W_conv) * dinv[row], bf16 out; W column in registers ------
__global__ __launch_bounds__(256) void k_gemm(const float* __restrict__ x,
                                              const float* __restrict__ W,
                                              const float* __restrict__ dinv,
                                              unsigned short* __restrict__ gm) {
    __shared__ float Wl[IN_DIM * HID];  // 32 KB
    __shared__ float xs[16][IN_DIM];    // 8 KB
    const int t = threadIdx.x;
    const float4* W4 = (const float4*)W;
    for (int i = t; i < IN_DIM * HID / 4; i += 256) ((float4*)Wl)[i] = W4[i];
    const int base = blockIdx.x * 16;
    const float4* x4 = (const float4*)(x + (size_t)base * IN_DIM);
    for (int i = t; i < 16 * IN_DIM / 4; i += 256) ((float4*)xs)[i] = x4[i];
    __syncthreads();
    const int d = t & 63, g = t >> 6;
    float wreg[IN_DIM];
#pragma unroll
    for (int k = 0; k < IN_DIM; k++) wreg[k] = Wl[k * HID + d];
    float a0 = 0.f, a1 = 0.f, a2 = 0.f, a3 = 0.f;
#pragma unroll
    for (int k = 0; k < IN_DIM; k += 4) {
        float4 xv0 = *(const float4*)&xs[g][k];
        float4 xv1 = *(const float4*)&xs[g + 4][k];
        float4 xv2 = *(const float4*)&xs[g + 8][k];
        float4 xv3 = *(const float4*)&xs[g + 12][k];
        a0 += xv0.x * wreg[k] + xv0.y * wreg[k + 1] + xv0.z * wreg[k + 2] + xv0.w * wreg[k + 3];
        a1 += xv1.x * wreg[k] + xv1.y * wreg[k + 1] + xv1.z * wreg[k + 2] + xv1.w * wreg[k + 3];
        a2 += xv2.x * wreg[k] + xv2.y * wreg[k + 1] + xv2.z * wreg[k + 2] + xv2.w * wreg[k + 3];
        a3 += xv3.x * wreg[k] + xv3.y * wreg[k + 1] + xv3.z * wreg[k + 2] + xv3.w * wreg[k + 3];
    }
    a0 *= dinv[base + g];
    a1 *= dinv[base + g + 4];
    a2 *= dinv[base + g + 8];
    a3 *= dinv[base + g + 12];
    gm[(size_t)(base + g) * HID + d]      = __bfloat16_as_ushort(__float2bfloat16(a0));
    gm[(size_t)(base + g + 4) * HID + d]  = __bfloat16_as_ushort(__float2bfloat16(a1));
    gm[(size_t)(base + g + 8) * HID + d]  = __bfloat16_as_ushort(__float2bfloat16(a2));
    gm[(size_t)(base + g + 12) * HID + d] = __bfloat16_as_ushort(__float2bfloat16(a3));
}

// ---------------- phase 1: bucketed scatter of packed records ----------------
// record = (c & 255) << 17 | r   (r < 2^17)
__global__ __launch_bounds__(512) void k_bucket(const int* __restrict__ src,
                                                const int* __restrict__ dst,
                                                int* __restrict__ gcur,
                                                unsigned* __restrict__ gbuf) {
    __shared__ int cnt[512];
    __shared__ int off[512];
    __shared__ int cur[NB];
    __shared__ int gbase[NB];
    __shared__ unsigned buf[EPB];
    __shared__ unsigned short bkt[EPB];
    const int t = threadIdx.x;
    const int e0 = blockIdx.x * EPB;
    const int n = min(EPB, N_EDGES - e0);
    cnt[t] = 0;
    __syncthreads();
    unsigned myrec[EPB / 512];
    int myb[EPB / 512];
#pragma unroll
    for (int k = 0; k < EPB / 512; k++) {
        int e = e0 + k * 512 + t;
        if (e < N_EDGES) {
            int r = src[e];
            int c = dst[e];
            int b = c >> 8;
            myrec[k] = ((unsigned)(c & 255) << 17) | (unsigned)r;
            myb[k] = b;
            atomicAdd(&cnt[b], 1);
        } else {
            myb[k] = -1;
        }
    }
    __syncthreads();
    int own = cnt[t];
    for (int o = 1; o < 512; o <<= 1) {
        int v = (t >= o) ? cnt[t - o] : 0;
        __syncthreads();
        cnt[t] += v;
        __syncthreads();
    }
    off[t] = cnt[t] - own;  // exclusive prefix
    if (t < NB) {
        cur[t] = off[t];
        gbase[t] = own ? atomicAdd(&gcur[t], own) : 0;
    }
    __syncthreads();
#pragma unroll
    for (int k = 0; k < EPB / 512; k++) {
        if (myb[k] >= 0) {
            int p = atomicAdd(&cur[myb[k]], 1);
            buf[p] = myrec[k];
            bkt[p] = (unsigned short)myb[k];
        }
    }
    __syncthreads();
    for (int j = t; j < n; j += 512) {
        int b = bkt[j];
        gbuf[gbase[b] + (j - off[b])] = buf[j];
    }
}

// ---------------- phase 2: per-bucket records -> CSR (localized writes) ------
__global__ __launch_bounds__(256) void k_csr(const unsigned* __restrict__ gbuf,
                                             const int* __restrict__ bucket_base,
                                             const int* __restrict__ cnt,
                                             int* __restrict__ row_start,
                                             int* __restrict__ srcs) {
    __shared__ int s[256];
    __shared__ int cur[256];
    const int b = blockIdx.x, t = threadIdx.x;
    const int c = b * 256 + t;
    int my = (c < N_NODES) ? cnt[c] : 0;
    s[t] = my;
    __syncthreads();
    for (int o = 1; o < 256; o <<= 1) {
        int v = (t >= o) ? s[t - o] : 0;
        __syncthreads();
        s[t] += v;
        __syncthreads();
    }
    int base = bucket_base[b] + s[t] - my;  // global exclusive prefix
    if (c < N_NODES) row_start[c] = base;
    cur[t] = base;
    if (b == NB - 1 && t == 0) row_start[N_NODES] = bucket_base[NB];
    __syncthreads();
    const int beg = bucket_base[b], end = bucket_base[b + 1];
    for (int j = beg + t; j < end; j += 256) {
        unsigned rec = gbuf[j];
        int cl = rec >> 17, r = rec & 0x1FFFF;
        int pos = atomicAdd(&cur[cl], 1);
        srcs[pos] = r;  // lands in this bucket's contiguous ~16KB window
    }
}

// ------- fused gather(bf16 g) + self + bias/relu/dropout + [64->2] matvec -------
__global__ __launch_bounds__(256) void k_aggr(const unsigned short* __restrict__ gm,
                                              const int* __restrict__ row_start,
                                              const int* __restrict__ srcs,
                                              const float* __restrict__ dinv,
                                              const float* __restrict__ bconv,
                                              const float* __restrict__ Wlin,
                                              const float* __restrict__ blin,
                                              float* __restrict__ out) {
    const int c = blockIdx.x * 4 + (threadIdx.x >> 6);
    const int d = threadIdx.x & 63;
    float acc = bf2f(gm[((unsigned)c << 6) + d]);  // self-loop term g[c]
    const int beg = row_start[c];
    const int end = row_start[c + 1];
    int j = beg;
    for (; j + 7 < end; j += 8) {
        int r[8];
#pragma unroll
        for (int u = 0; u < 8; u++) r[u] = srcs[j + u];
        float v[8];
#pragma unroll
        for (int u = 0; u < 8; u++) v[u] = bf2f(gm[((unsigned)r[u] << 6) + d]);
#pragma unroll
        for (int u = 0; u < 8; u++) acc += v[u];
    }
    for (; j < end; j++) {
        acc += bf2f(gm[((unsigned)srcs[j] << 6) + d]);
    }
    float v = acc * dinv[c] + bconv[d];
    v = fmaxf(v, 0.f);
    unsigned i = (unsigned)(c * HID + d);
    unsigned o0, o1;
    threefry2x32_k42(0u, i, o0, o1);
    v = ((o0 ^ o1) & 0x80000000u) ? 0.f : v * 2.f;
    float a0 = v * Wlin[d * 2 + 0];
    float a1 = v * Wlin[d * 2 + 1];
#pragma unroll
    for (int off = 32; off; off >>= 1) {
        a0 += __shfl_down(a0, off);
        a1 += __shfl_down(a1, off);
    }
    if (d == 0) {
        out[(size_t)c * 2 + 0] = a0 + blin[0];
        out[(size_t)c * 2 + 1] = a1 + blin[1];
    }
}

extern "C" void kernel_launch(void* const* d_in, const int* in_sizes, int n_in,
                              void* d_out, int out_size, void* d_ws, size_t ws_size,
                              hipStream_t stream) {
    // Map inputs BY ELEMENT COUNT (all unique) — robust to positional order.
    const float* x  = (const float*)d_in[0];
    const void*  ei = d_in[1];
    const float* Wc = (const float*)d_in[2];
    const float* bc = (const float*)d_in[3];
    const float* Wl = (const float*)d_in[4];
    const float* bl = (const float*)d_in[5];
    for (int i = 0; i < n_in; i++) {
        switch (in_sizes[i]) {
            case N_NODES * IN_DIM:   x  = (const float*)d_in[i]; break;
            case 2 * N_EDGES:
            case 4 * N_EDGES:        ei = d_in[i]; break;
            case IN_DIM * HID:       Wc = (const float*)d_in[i]; break;
            case HID:                bc = (const float*)d_in[i]; break;
            case HID * 2:            Wl = (const float*)d_in[i]; break;
            case 2:                  bl = (const float*)d_in[i]; break;
            default: break;
        }
    }
    float* out = (float*)d_out;

    const int* src = (const int*)ei;            // edge_index[0] (int32, proven)
    const int* dst = (const int*)ei + N_EDGES;  // edge_index[1]

    char* ws = (char*)d_ws;
    size_t off = 0;
    unsigned short* gm    = (unsigned short*)(ws + off); off += (size_t)N_NODES * HID * 2;  // 12.8 MB
    int*      cnt         = (int*)(ws + off);      off += (size_t)N_NODES * 4;
    float*    dinv        = (float*)(ws + off);    off += (size_t)N_NODES * 4;
    int*      row_start   = (int*)(ws + off);      off += (size_t)(N_NODES + 4) * 4;
    int*      bucketsum   = (int*)(ws + off);      off += (size_t)(NB + 4) * 4;
    int*      bucket_base = (int*)(ws + off);      off += (size_t)(NB + 4) * 4;
    int*      gcur        = (int*)(ws + off);      off += (size_t)(NB + 4) * 4;
    unsigned* gbuf        = (unsigned*)(ws + off); off += (size_t)N_EDGES * 4;        // 6.4 MB
    int*      srcs        = (int*)(ws + off);      off += (size_t)N_EDGES * 4;        // 6.4 MB

    hipMemsetAsync(cnt, 0, (size_t)N_NODES * 4, stream);
    k_hist<<<(N_EDGES + 255) / 256, 256, 0, stream>>>(dst, cnt);
    k_scanA<<<NB, 256, 0, stream>>>(cnt, bucketsum, dinv);
    k_scanB<<<1, 512, 0, stream>>>(bucketsum, bucket_base, gcur);
    k_gemm<<<N_NODES / 16, 256, 0, stream>>>(x, Wc, dinv, gm);
    k_bucket<<<BUCKET_BLOCKS, 512, 0, stream>>>(src, dst, gcur, gbuf);
    k_csr<<<NB, 256, 0, stream>>>(gbuf, bucket_base, cnt, row_start, srcs);
    k_aggr<<<N_NODES / 4, 256, 0, stream>>>(gm, row_start, srcs, dinv, bc, Wl, bl, out);
}

// Round 17
// 237.329 us; speedup vs baseline: 1.3185x; 1.3185x over previous
//
#include <hip/hip_runtime.h>
#include <hip/hip_bf16.h>

#define N_NODES 100000
#define N_EDGES 1600000
#define IN_DIM 128
#define HID 64
#define NB ((N_NODES + 255) / 256)          // 391 buckets of 256 dst nodes
#define EPB 4096                            // edges per k_bucket block
#define BUCKET_BLOCKS ((N_EDGES + EPB - 1) / EPB)  // 391
#define MAXPB 8192                          // fixed gbuf region per bucket (mean 4092)

// ---------------- threefry2x32, key = (0, 42) ----------------
__device__ __forceinline__ unsigned rotl32(unsigned x, unsigned r) {
    return (x << r) | (x >> (32u - r));
}

__device__ __forceinline__ void threefry2x32_k42(unsigned x0, unsigned x1,
                                                 unsigned& o0, unsigned& o1) {
    const unsigned ks0 = 0u;
    const unsigned ks1 = 42u;
    const unsigned ks2 = 0u ^ 42u ^ 0x1BD11BDAu;
    x0 += ks0; x1 += ks1;
    x0 += x1; x1 = rotl32(x1, 13); x1 ^= x0;
    x0 += x1; x1 = rotl32(x1, 15); x1 ^= x0;
    x0 += x1; x1 = rotl32(x1, 26); x1 ^= x0;
    x0 += x1; x1 = rotl32(x1, 6);  x1 ^= x0;
    x0 += ks1; x1 += ks2 + 1u;
    x0 += x1; x1 = rotl32(x1, 17); x1 ^= x0;
    x0 += x1; x1 = rotl32(x1, 29); x1 ^= x0;
    x0 += x1; x1 = rotl32(x1, 16); x1 ^= x0;
    x0 += x1; x1 = rotl32(x1, 24); x1 ^= x0;
    x0 += ks2; x1 += ks0 + 2u;
    x0 += x1; x1 = rotl32(x1, 13); x1 ^= x0;
    x0 += x1; x1 = rotl32(x1, 15); x1 ^= x0;
    x0 += x1; x1 = rotl32(x1, 26); x1 ^= x0;
    x0 += x1; x1 = rotl32(x1, 6);  x1 ^= x0;
    x0 += ks0; x1 += ks1 + 3u;
    x0 += x1; x1 = rotl32(x1, 17); x1 ^= x0;
    x0 += x1; x1 = rotl32(x1, 29); x1 ^= x0;
    x0 += x1; x1 = rotl32(x1, 16); x1 ^= x0;
    x0 += x1; x1 = rotl32(x1, 24); x1 ^= x0;
    x0 += ks1; x1 += ks2 + 4u;
    x0 += x1; x1 = rotl32(x1, 13); x1 ^= x0;
    x0 += x1; x1 = rotl32(x1, 15); x1 ^= x0;
    x0 += x1; x1 = rotl32(x1, 26); x1 ^= x0;
    x0 += x1; x1 = rotl32(x1, 6);  x1 ^= x0;
    x0 += ks2; x1 += ks0 + 5u;
    o0 = x0; o1 = x1;
}

__device__ __forceinline__ float bf2f(unsigned short u) {
    return __uint_as_float((unsigned)u << 16);
}

// ---- phase 1: bucketed scatter into FIXED regions (no scan dependency) ----
// record = (c & 255) << 17 | r   (r < 2^17)
__global__ __launch_bounds__(512) void k_bucket(const int* __restrict__ src,
                                                const int* __restrict__ dst,
                                                int* __restrict__ bucketcnt,
                                                unsigned* __restrict__ gbuf) {
    __shared__ int cnt[512];
    __shared__ int off[512];
    __shared__ int cur[NB];
    __shared__ int gbase[NB];
    __shared__ unsigned buf[EPB];
    __shared__ unsigned short bkt[EPB];
    const int t = threadIdx.x;
    const int e0 = blockIdx.x * EPB;
    const int n = min(EPB, N_EDGES - e0);
    cnt[t] = 0;
    __syncthreads();
    unsigned myrec[EPB / 512];
    int myb[EPB / 512];
#pragma unroll
    for (int k = 0; k < EPB / 512; k++) {
        int e = e0 + k * 512 + t;
        if (e < N_EDGES) {
            int r = src[e];
            int c = dst[e];
            int b = c >> 8;
            myrec[k] = ((unsigned)(c & 255) << 17) | (unsigned)r;
            myb[k] = b;
            atomicAdd(&cnt[b], 1);
        } else {
            myb[k] = -1;
        }
    }
    __syncthreads();
    int own = cnt[t];
    for (int o = 1; o < 512; o <<= 1) {
        int v = (t >= o) ? cnt[t - o] : 0;
        __syncthreads();
        cnt[t] += v;
        __syncthreads();
    }
    off[t] = cnt[t] - own;  // exclusive prefix (records sorted by bucket in buf)
    if (t < NB) {
        cur[t] = off[t];
        gbase[t] = t * MAXPB + (own ? atomicAdd(&bucketcnt[t], own) : 0);
    }
    __syncthreads();
#pragma unroll
    for (int k = 0; k < EPB / 512; k++) {
        if (myb[k] >= 0) {
            int p = atomicAdd(&cur[myb[k]], 1);
            buf[p] = myrec[k];
            bkt[p] = (unsigned short)myb[k];
        }
    }
    __syncthreads();
    for (int j = t; j < n; j += 512) {
        int b = bkt[j];
        gbuf[gbase[b] + (j - off[b])] = buf[j];
    }
}

// ---- exclusive scan over NB bucket totals -> bucket_base ----
__global__ __launch_bounds__(512) void k_scanB(const int* __restrict__ bucketcnt,
                                               int* __restrict__ bucket_base) {
    __shared__ int s[512];
    int t = threadIdx.x;
    int own = (t < NB) ? bucketcnt[t] : 0;
    s[t] = own;
    __syncthreads();
    for (int o = 1; o < 512; o <<= 1) {
        int v = (t >= o) ? s[t - o] : 0;
        __syncthreads();
        s[t] += v;
        __syncthreads();
    }
    if (t < NB) bucket_base[t] = s[t] - own;
    if (t == 511) bucket_base[NB] = s[511];  // = N_EDGES
}

// ---- phase 2: per-bucket count + scan + row_start + dinv + distribute ----
// Replaces k_hist/k_scanA/k_csr: degrees counted from the bucket's own records.
__global__ __launch_bounds__(256) void k_csr2(const unsigned* __restrict__ gbuf,
                                              const int* __restrict__ bucketcnt,
                                              const int* __restrict__ bucket_base,
                                              int* __restrict__ row_start,
                                              float* __restrict__ dinv,
                                              int* __restrict__ srcs) {
    __shared__ unsigned lbuf[MAXPB];  // 32 KB
    __shared__ int lcnt[256];
    __shared__ int pre[256];
    __shared__ int cur[256];
    const int b = blockIdx.x, t = threadIdx.x;
    const int n = bucketcnt[b];
    const unsigned* reg = gbuf + (size_t)b * MAXPB;
    lcnt[t] = 0;
    for (int j = t; j < n; j += 256) lbuf[j] = reg[j];
    __syncthreads();
    for (int j = t; j < n; j += 256) atomicAdd(&lcnt[lbuf[j] >> 17], 1);
    __syncthreads();
    int my = lcnt[t];
    pre[t] = my;
    __syncthreads();
    for (int o = 1; o < 256; o <<= 1) {
        int v = (t >= o) ? pre[t - o] : 0;
        __syncthreads();
        pre[t] += v;
        __syncthreads();
    }
    const int gb = bucket_base[b];
    int base = gb + pre[t] - my;  // global exclusive prefix
    cur[t] = base;
    const int c = b * 256 + t;
    if (c < N_NODES) {
        row_start[c] = base;
        dinv[c] = rsqrtf((float)(my + 1));  // in-degree + self-loop
    }
    if (b == NB - 1 && t == 255) row_start[N_NODES] = gb + pre[255];
    __syncthreads();
    for (int j = t; j < n; j += 256) {
        unsigned rec = lbuf[j];
        int pos = atomicAdd(&cur[rec >> 17], 1);
        srcs[pos] = (int)(rec & 0x1FFFF);  // localized ~16KB window per bucket
    }
}

// ------ g = (x @ W_conv) * dinv[row], bf16 out; W column in registers ------
__global__ __launch_bounds__(256) void k_gemm(const float* __restrict__ x,
                                              const float* __restrict__ W,
                                              const float* __restrict__ dinv,
                                              unsigned short* __restrict__ gm) {
    __shared__ float Wl[IN_DIM * HID];  // 32 KB
    __shared__ float xs[16][IN_DIM];    // 8 KB
    const int t = threadIdx.x;
    const float4* W4 = (const float4*)W;
    for (int i = t; i < IN_DIM * HID / 4; i += 256) ((float4*)Wl)[i] = W4[i];
    const int base = blockIdx.x * 16;
    const float4* x4 = (const float4*)(x + (size_t)base * IN_DIM);
    for (int i = t; i < 16 * IN_DIM / 4; i += 256) ((float4*)xs)[i] = x4[i];
    __syncthreads();
    const int d = t & 63, g = t >> 6;
    float wreg[IN_DIM];
#pragma unroll
    for (int k = 0; k < IN_DIM; k++) wreg[k] = Wl[k * HID + d];
    float a0 = 0.f, a1 = 0.f, a2 = 0.f, a3 = 0.f;
#pragma unroll
    for (int k = 0; k < IN_DIM; k += 4) {
        float4 xv0 = *(const float4*)&xs[g][k];
        float4 xv1 = *(const float4*)&xs[g + 4][k];
        float4 xv2 = *(const float4*)&xs[g + 8][k];
        float4 xv3 = *(const float4*)&xs[g + 12][k];
        a0 += xv0.x * wreg[k] + xv0.y * wreg[k + 1] + xv0.z * wreg[k + 2] + xv0.w * wreg[k + 3];
        a1 += xv1.x * wreg[k] + xv1.y * wreg[k + 1] + xv1.z * wreg[k + 2] + xv1.w * wreg[k + 3];
        a2 += xv2.x * wreg[k] + xv2.y * wreg[k + 1] + xv2.z * wreg[k + 2] + xv2.w * wreg[k + 3];
        a3 += xv3.x * wreg[k] + xv3.y * wreg[k + 1] + xv3.z * wreg[k + 2] + xv3.w * wreg[k + 3];
    }
    a0 *= dinv[base + g];
    a1 *= dinv[base + g + 4];
    a2 *= dinv[base + g + 8];
    a3 *= dinv[base + g + 12];
    gm[(size_t)(base + g) * HID + d]      = __bfloat16_as_ushort(__float2bfloat16(a0));
    gm[(size_t)(base + g + 4) * HID + d]  = __bfloat16_as_ushort(__float2bfloat16(a1));
    gm[(size_t)(base + g + 8) * HID + d]  = __bfloat16_as_ushort(__float2bfloat16(a2));
    gm[(size_t)(base + g + 12) * HID + d] = __bfloat16_as_ushort(__float2bfloat16(a3));
}

// ------- fused gather(bf16 g) + self + bias/relu/dropout + [64->2] matvec -------
__global__ __launch_bounds__(256) void k_aggr(const unsigned short* __restrict__ gm,
                                              const int* __restrict__ row_start,
                                              const int* __restrict__ srcs,
                                              const float* __restrict__ dinv,
                                              const float* __restrict__ bconv,
                                              const float* __restrict__ Wlin,
                                              const float* __restrict__ blin,
                                              float* __restrict__ out) {
    const int c = blockIdx.x * 4 + (threadIdx.x >> 6);
    const int d = threadIdx.x & 63;
    float acc = bf2f(gm[((unsigned)c << 6) + d]);  // self-loop term g[c]
    const int beg = row_start[c];
    const int end = row_start[c + 1];
    int j = beg;
    for (; j + 7 < end; j += 8) {
        int r[8];
#pragma unroll
        for (int u = 0; u < 8; u++) r[u] = srcs[j + u];
        float v[8];
#pragma unroll
        for (int u = 0; u < 8; u++) v[u] = bf2f(gm[((unsigned)r[u] << 6) + d]);
#pragma unroll
        for (int u = 0; u < 8; u++) acc += v[u];
    }
    for (; j < end; j++) {
        acc += bf2f(gm[((unsigned)srcs[j] << 6) + d]);
    }
    float v = acc * dinv[c] + bconv[d];
    v = fmaxf(v, 0.f);
    unsigned i = (unsigned)(c * HID + d);
    unsigned o0, o1;
    threefry2x32_k42(0u, i, o0, o1);
    v = ((o0 ^ o1) & 0x80000000u) ? 0.f : v * 2.f;
    float a0 = v * Wlin[d * 2 + 0];
    float a1 = v * Wlin[d * 2 + 1];
#pragma unroll
    for (int off = 32; off; off >>= 1) {
        a0 += __shfl_down(a0, off);
        a1 += __shfl_down(a1, off);
    }
    if (d == 0) {
        out[(size_t)c * 2 + 0] = a0 + blin[0];
        out[(size_t)c * 2 + 1] = a1 + blin[1];
    }
}

extern "C" void kernel_launch(void* const* d_in, const int* in_sizes, int n_in,
                              void* d_out, int out_size, void* d_ws, size_t ws_size,
                              hipStream_t stream) {
    // Map inputs BY ELEMENT COUNT (all unique) — robust to positional order.
    const float* x  = (const float*)d_in[0];
    const void*  ei = d_in[1];
    const float* Wc = (const float*)d_in[2];
    const float* bc = (const float*)d_in[3];
    const float* Wl = (const float*)d_in[4];
    const float* bl = (const float*)d_in[5];
    for (int i = 0; i < n_in; i++) {
        switch (in_sizes[i]) {
            case N_NODES * IN_DIM:   x  = (const float*)d_in[i]; break;
            case 2 * N_EDGES:
            case 4 * N_EDGES:        ei = d_in[i]; break;
            case IN_DIM * HID:       Wc = (const float*)d_in[i]; break;
            case HID:                bc = (const float*)d_in[i]; break;
            case HID * 2:            Wl = (const float*)d_in[i]; break;
            case 2:                  bl = (const float*)d_in[i]; break;
            default: break;
        }
    }
    float* out = (float*)d_out;

    const int* src = (const int*)ei;            // edge_index[0] (int32, proven r2≡r3)
    const int* dst = (const int*)ei + N_EDGES;  // edge_index[1]

    char* ws = (char*)d_ws;
    size_t off = 0;
    unsigned short* gm    = (unsigned short*)(ws + off); off += (size_t)N_NODES * HID * 2;  // 12.8 MB
    float*    dinv        = (float*)(ws + off);    off += (size_t)N_NODES * 4;
    int*      row_start   = (int*)(ws + off);      off += (size_t)(N_NODES + 4) * 4;
    int*      bucketcnt   = (int*)(ws + off);      off += (size_t)(NB + 4) * 4;
    int*      bucket_base = (int*)(ws + off);      off += (size_t)(NB + 4) * 4;
    unsigned* gbuf        = (unsigned*)(ws + off); off += (size_t)NB * MAXPB * 4;     // 12.8 MB
    int*      srcs        = (int*)(ws + off);      off += (size_t)N_EDGES * 4;        // 6.4 MB

    hipMemsetAsync(bucketcnt, 0, (size_t)NB * 4, stream);
    k_bucket<<<BUCKET_BLOCKS, 512, 0, stream>>>(src, dst, bucketcnt, gbuf);
    k_scanB<<<1, 512, 0, stream>>>(bucketcnt, bucket_base);
    k_csr2<<<NB, 256, 0, stream>>>(gbuf, bucketcnt, bucket_base, row_start, dinv, srcs);
    k_gemm<<<N_NODES / 16, 256, 0, stream>>>(x, Wc, dinv, gm);
    k_aggr<<<N_NODES / 4, 256, 0, stream>>>(gm, row_start, srcs, dinv, bc, Wl, bl, out);
}